// Round 11
// baseline (355.578 us; speedup 1.0000x reference)
//
#include <hip/hip_runtime.h>

#define GRID_D 64
#define NN (GRID_D * GRID_D)   // 4096 nodes per image
#define H 64
#define C_IN 12
#define B_SZ 128
#define LN_EPS 1e-5f

typedef _Float16 f16x8 __attribute__((ext_vector_type(8)));
typedef _Float16 f16x4 __attribute__((ext_vector_type(4)));
typedef float    f32x4 __attribute__((ext_vector_type(4)));

// dynamic LDS: ring[2][4][4096] f16 (64KB) | pl[640] f32 (2.5KB)
#define SMEM_BYTES (2 * 4 * 4096 * 2 + 640 * 4)   // 68,096 B -> 2 blocks/CU

// ---------------------------------------------------------------------------
// Kernel 0: weight prep — plain-transposed f16 copies of Ws/Wn.
// wt[l][g][j][k] = W[l,g][k][j]
// ---------------------------------------------------------------------------
__global__ __launch_bounds__(256) void k_prep(
    const float* __restrict__ ws_, const float* __restrict__ wn_,
    _Float16* __restrict__ wt)
{
    int i = blockIdx.x * 256 + threadIdx.x;      // 0..24575
    if (i < 3 * 2 * 4096) {
        int l = i >> 13, g = (i >> 12) & 1, j = (i >> 6) & 63, k = i & 63;
        const float* W = (g ? wn_ : ws_) + l * 4096;
        wt[i] = (_Float16)W[k * 64 + j];
    }
}

// ---------------------------------------------------------------------------
// Kernel 1: input projection  h0[b,n,j] = sum_c x[b,c,n] * w_in[c,j] + b_in[j]
// ---------------------------------------------------------------------------
__global__ __launch_bounds__(256) void k_inproj(
    const float* __restrict__ x, const float* __restrict__ w_in,
    const float* __restrict__ b_in, _Float16* __restrict__ h)
{
    int bid = blockIdx.x;            // b*64 + r
    int b = bid >> 6, r = bid & 63;
    __shared__ float xs[C_IN][GRID_D];
    __shared__ float ws[C_IN][H];
    int tid = threadIdx.x;
    const float* xb = x + (size_t)b * C_IN * NN + (size_t)r * GRID_D;
    for (int idx = tid; idx < C_IN * GRID_D; idx += 256) {
        int c = idx >> 6, n = idx & 63;
        xs[c][n] = xb[(size_t)c * NN + n];
        ws[c][n] = w_in[idx];
    }
    __syncthreads();
    int n = tid >> 2;                // node 0..63
    int j0 = (tid & 3) * 16;         // 16-feat group
    float acc[16];
    #pragma unroll
    for (int t = 0; t < 16; ++t) acc[t] = b_in[j0 + t];
    #pragma unroll
    for (int c = 0; c < C_IN; ++c) {
        float xv = xs[c][n];
        #pragma unroll
        for (int t = 0; t < 16; ++t) acc[t] += xv * ws[c][j0 + t];
    }
    _Float16* hp = h + (size_t)(b * NN + r * GRID_D + n) * H + j0;
    f16x8 o0, o1;
    #pragma unroll
    for (int t = 0; t < 8; ++t) { o0[t] = (_Float16)acc[t]; o1[t] = (_Float16)acc[8 + t]; }
    *(f16x8*)hp = o0;
    *(f16x8*)(hp + 8) = o1;
}

// ---------------------------------------------------------------------------
// Kernel 2: FUSED 3 layers + head, wavefront pipeline, NO ring0.
// Block = 768 thr (12 waves) owns 32 output rows of one image (grid 256).
// grp0 (waves 0-3): h1 from GLOBAL h0 (L1/L2-hot: each row touched 3x in 3
// consecutive steps) -> ring0. grp1: h1->h2 (ring0->ring1). grp2: h2->h3+head
// -> logits. Step s: grp g computes row r0-2-2g+s; one barrier/step; ring
// reads are >=1 step older than writes. LDS 68KB -> 2 blocks/CU (24 waves).
// Weights: 16 f16x8/lane in VGPRs, pinned.
// ---------------------------------------------------------------------------
__global__ __launch_bounds__(768, 6) void k_fused(
    const _Float16* __restrict__ h0, float* __restrict__ logits,
    const _Float16* __restrict__ wtb,      // [3][2][64][64] transposed f16
    const float* __restrict__ cb, const float* __restrict__ lg,
    const float* __restrict__ lb,
    const float* __restrict__ w_head, const float* __restrict__ b_head)
{
    extern __shared__ _Float16 smem[];
    _Float16* ringb = smem;                // [2][4][4096]
    float*    pl    = (float*)(smem + 32768);   // 640 f32

    int tid = threadIdx.x, ln = tid & 63, wv = tid >> 6;
    int bid = blockIdx.x;
    int img = bid >> 1, chunk = bid & 1;
    int r0 = chunk << 5;                   // 32 output rows
    const _Float16* hg = h0 + ((size_t)img << 18);

    int grp = wv >> 2;                     // 0,1,2 = layer-1,2,3
    int ct  = wv & 3;                      // col tile
    int lrow = ln & 15, kgrp = ln >> 4;
    int col = ct * 16 + lrow;
    int cs = col & 7;                      // == lrow & 7
    int kq = kgrp * 4;
    bool cl = (col > 0), cr = (col < 63);

    // ---- weights for my group's layer: 16 frags = 64 VGPR, pinned ----
    const _Float16* wg = wtb + grp * 8192;
    f16x8 wsf[2][4], wnf[2][4];
    #pragma unroll
    for (int ks = 0; ks < 2; ++ks) {
        int k0 = ks * 32 + kq * 2;         // ks*32 + kgrp*8
        #pragma unroll
        for (int ft = 0; ft < 4; ++ft) {
            int j = ft * 16 + lrow;
            wsf[ks][ft] = *(const f16x8*)(wg + (j << 6) + k0);
            wnf[ks][ft] = *(const f16x8*)(wg + ((64 + j) << 6) + k0);
        }
    }
    #pragma unroll
    for (int ks = 0; ks < 2; ++ks)
        #pragma unroll
        for (int ft = 0; ft < 4; ++ft)
            asm volatile("" : "+v"(wsf[ks][ft]), "+v"(wnf[ks][ft]));

    // ---- params to LDS ----
    if (tid < 576) {
        int l = tid / 192, r = tid % 192;
        pl[tid] = (r < 64) ? cb[l * 64 + r]
                : (r < 128) ? lg[l * 64 + r - 64] : lb[l * 64 + r - 128];
    } else if (tid < 640) {
        pl[tid] = w_head[tid - 576];
    }
    __syncthreads();

    const float* myp = pl + grp * 192;
    float bh = b_head[0];

    // compute validity range per group (clipped to image rows)
    int qoff = -2 - 2 * grp;
    int loC, hiC;
    if (grp == 0)      { loC = (r0 - 2 < 0) ? 0 : r0 - 2; hiC = (r0 + 33 > 63) ? 63 : r0 + 33; }
    else if (grp == 1) { loC = (r0 - 1 < 0) ? 0 : r0 - 1; hiC = (r0 + 32 > 63) ? 63 : r0 + 32; }
    else               { loC = r0;                         hiC = r0 + 31; }

    _Float16* rin  = (grp == 1) ? ringb : ringb + 16384;   // grp2 reads ring1
    _Float16* rout = (grp == 0) ? ringb : ringb + 16384;   // grp1 writes ring1

    #pragma unroll 1
    for (int s = 0; s <= 37; ++s) {
        int q = r0 + qoff + s;                 // my group's row this step
        if (q >= loC && q <= hiC) {
            _Float16 hinv = (_Float16)(1.0f / (float)((q > 0) + (q < 63) + cl + cr));
            f16x8 selfA[2], aggA[2];
            f16x8 z = {};
            const _Float16* rp = hg + ((size_t)q << 12);    // global row base (grp0)
            const _Float16* rc = rin + ((q & 3) << 12);     // ring row (grp1/2)

            if (grp == 0) {
                bool mu = (q > 0), md = (q < 63);
                #pragma unroll
                for (int ks = 0; ks < 2; ++ks) {
                    int k0 = ks * 32 + kq * 2;
                    const _Float16* pc = rp + (col << 6) + k0;
                    selfA[ks] = *(const f16x8*)pc;
                    f16x8 u = mu ? *(const f16x8*)(pc - 4096) : z;
                    f16x8 d = md ? *(const f16x8*)(pc + 4096) : z;
                    f16x8 l = cl ? *(const f16x8*)(pc - 64)   : z;
                    f16x8 r = cr ? *(const f16x8*)(pc + 64)   : z;
                    f16x8 sm = (l + r) + (u + d);
                    f16x8 g;
                    #pragma unroll
                    for (int e = 0; e < 8; ++e) g[e] = sm[e] * hinv;
                    aggA[ks] = g;
                }
            } else {
                const _Float16* ru = rin + (((q - 1) & 3) << 12);
                const _Float16* rd = rin + (((q + 1) & 3) << 12);
                #pragma unroll
                for (int ks = 0; ks < 2; ++ks) {
                    int c8 = ks * 4 + kgrp;
                    int sl = (c8 ^ cs) << 3;
                    selfA[ks] = *(const f16x8*)(rc + (col << 6) + sl);
                    f16x8 u = (q > 0)  ? *(const f16x8*)(ru + (col << 6) + sl) : z;
                    f16x8 d = (q < 63) ? *(const f16x8*)(rd + (col << 6) + sl) : z;
                    int cm = col - cl;
                    f16x8 l = *(const f16x8*)(rc + (cm << 6) + ((c8 ^ (cm & 7)) << 3));
                    if (!cl) l = z;
                    int cp = col + cr;
                    f16x8 r = *(const f16x8*)(rc + (cp << 6) + ((c8 ^ (cp & 7)) << 3));
                    if (!cr) r = z;
                    f16x8 sm = (l + r) + (u + d);
                    f16x8 g;
                    #pragma unroll
                    for (int e = 0; e < 8; ++e) g[e] = sm[e] * hinv;
                    aggA[ks] = g;
                }
            }

            f32x4 acc[4];
            #pragma unroll
            for (int ft = 0; ft < 4; ++ft) acc[ft] = (f32x4){0.f, 0.f, 0.f, 0.f};
            #pragma unroll
            for (int ks = 0; ks < 2; ++ks)
                #pragma unroll
                for (int ft = 0; ft < 4; ++ft)
                    acc[ft] = __builtin_amdgcn_mfma_f32_16x16x32_f16(wsf[ks][ft], selfA[ks], acc[ft], 0, 0, 0);
            #pragma unroll
            for (int ks = 0; ks < 2; ++ks)
                #pragma unroll
                for (int ft = 0; ft < 4; ++ft)
                    acc[ft] = __builtin_amdgcn_mfma_f32_16x16x32_f16(wnf[ks][ft], aggA[ks], acc[ft], 0, 0, 0);

            // ---- epilogue: +bias, LN, residual+ReLU -> ring or logits ----
            float s1 = 0.f, s2 = 0.f;
            #pragma unroll
            for (int ft = 0; ft < 4; ++ft) {
                f32x4 qv = *(const f32x4*)&myp[ft * 16 + kq];
                acc[ft] += qv;
                #pragma unroll
                for (int t = 0; t < 4; ++t) { float xv = acc[ft][t]; s1 += xv; s2 += xv * xv; }
            }
            s1 += __shfl_xor(s1, 16); s1 += __shfl_xor(s1, 32);
            s2 += __shfl_xor(s2, 16); s2 += __shfl_xor(s2, 32);
            float mu   = s1 * (1.0f / H);
            float var  = s2 * (1.0f / H) - mu * mu;
            float rstd = rsqrtf(var + LN_EPS);

            if (grp < 2) {
                _Float16* outp = rout + ((q & 3) << 12) + (col << 6);
                #pragma unroll
                for (int ft = 0; ft < 4; ++ft) {
                    f32x4 lgq = *(const f32x4*)&myp[64 + ft * 16 + kq];
                    f32x4 lbq = *(const f32x4*)&myp[128 + ft * 16 + kq];
                    int slot = (ft * 2 + (kgrp >> 1)) ^ cs;
                    f16x4 rq;
                    if (grp == 0)
                        rq = *(const f16x4*)(rp + (col << 6) + ft * 16 + kq);
                    else
                        rq = *(const f16x4*)(rc + (col << 6) + (slot << 3) + (kgrp & 1) * 4);
                    f16x4 oq;
                    #pragma unroll
                    for (int t = 0; t < 4; ++t) {
                        float o = (float)rq[t]
                                + fmaxf((acc[ft][t] - mu) * rstd * lgq[t] + lbq[t], 0.f);
                        oq[t] = (_Float16)o;
                    }
                    *(f16x4*)(outp + (slot << 3) + (kgrp & 1) * 4) = oq;
                }
            } else {
                float part = 0.f;
                #pragma unroll
                for (int ft = 0; ft < 4; ++ft) {
                    f32x4 lgq = *(const f32x4*)&myp[64 + ft * 16 + kq];
                    f32x4 lbq = *(const f32x4*)&myp[128 + ft * 16 + kq];
                    f32x4 whq = *(const f32x4*)&pl[576 + ft * 16 + kq];
                    int slot = (ft * 2 + (kgrp >> 1)) ^ cs;
                    f16x4 rq = *(const f16x4*)(rc + (col << 6) + (slot << 3) + (kgrp & 1) * 4);
                    #pragma unroll
                    for (int t = 0; t < 4; ++t) {
                        float o = (float)rq[t]
                                + fmaxf((acc[ft][t] - mu) * rstd * lgq[t] + lbq[t], 0.f);
                        part += o * whq[t];
                    }
                }
                part += __shfl_xor(part, 16);
                part += __shfl_xor(part, 32);
                if (kgrp == 0)
                    logits[(size_t)img * NN + q * GRID_D + col] = part + bh;
            }
        }
        __syncthreads();   // publishes ring writes for next step's readers
    }
}

// ---------------------------------------------------------------------------
extern "C" void kernel_launch(void* const* d_in, const int* in_sizes, int n_in,
                              void* d_out, int out_size, void* d_ws, size_t ws_size,
                              hipStream_t stream) {
    const float* x      = (const float*)d_in[0];
    // d_in[1] edge_index: fixed grid 4-neighborhood -> computed as stencil, unused
    const float* w_in   = (const float*)d_in[2];
    const float* b_in   = (const float*)d_in[3];
    const float* w_self = (const float*)d_in[4];
    const float* w_neigh= (const float*)d_in[5];
    const float* conv_b = (const float*)d_in[6];
    const float* ln_g   = (const float*)d_in[7];
    const float* ln_b   = (const float*)d_in[8];
    const float* w_head = (const float*)d_in[9];
    const float* b_head = (const float*)d_in[10];
    float* out = (float*)d_out;

    char* base = (char*)d_ws;
    const size_t HBYTES = (size_t)B_SZ * NN * H * sizeof(_Float16);   // 64 MiB
    _Float16* h_a = (_Float16*)base;
    _Float16* wtb = (_Float16*)(base + HBYTES);                       // 48 KiB

    (void)hipFuncSetAttribute(reinterpret_cast<const void*>(&k_fused),
                              hipFuncAttributeMaxDynamicSharedMemorySize, SMEM_BYTES);

    k_prep<<<96, 256, 0, stream>>>(w_self, w_neigh, wtb);
    k_inproj<<<B_SZ * GRID_D, 256, 0, stream>>>(x, w_in, b_in, h_a);
    k_fused<<<B_SZ * 2, 768, SMEM_BYTES, stream>>>(
        h_a, out, wtb, conv_b, ln_g, ln_b, w_head, b_head);
}

// Round 12
// 187.503 us; speedup vs baseline: 1.8964x; 1.8964x over previous
//
#include <hip/hip_runtime.h>

#define GRID_D 64
#define NN (GRID_D * GRID_D)   // 4096 nodes per image
#define H 64
#define C_IN 12
#define B_SZ 128
#define LN_EPS 1e-5f

typedef _Float16 f16x8 __attribute__((ext_vector_type(8)));
typedef _Float16 f16x4 __attribute__((ext_vector_type(4)));
typedef float    f32x4 __attribute__((ext_vector_type(4)));

// dynamic LDS: ring[2][4][4096] f16 (64KB) | pl[640] f32 (2.5KB)
#define SMEM_BYTES (2 * 4 * 4096 * 2 + 640 * 4)   // 68,096 B -> 2 blocks/CU if VGPR<=85

// ---------------------------------------------------------------------------
// Kernel 0: weight prep — plain-transposed f16 copies of Ws/Wn.
// wt[l][g][j][k] = W[l,g][k][j]
// ---------------------------------------------------------------------------
__global__ __launch_bounds__(256) void k_prep(
    const float* __restrict__ ws_, const float* __restrict__ wn_,
    _Float16* __restrict__ wt)
{
    int i = blockIdx.x * 256 + threadIdx.x;      // 0..24575
    if (i < 3 * 2 * 4096) {
        int l = i >> 13, g = (i >> 12) & 1, j = (i >> 6) & 63, k = i & 63;
        const float* W = (g ? wn_ : ws_) + l * 4096;
        wt[i] = (_Float16)W[k * 64 + j];
    }
}

// ---------------------------------------------------------------------------
// Kernel 1: input projection  h0[b,n,j] = sum_c x[b,c,n] * w_in[c,j] + b_in[j]
// ---------------------------------------------------------------------------
__global__ __launch_bounds__(256) void k_inproj(
    const float* __restrict__ x, const float* __restrict__ w_in,
    const float* __restrict__ b_in, _Float16* __restrict__ h)
{
    int bid = blockIdx.x;            // b*64 + r
    int b = bid >> 6, r = bid & 63;
    __shared__ float xs[C_IN][GRID_D];
    __shared__ float ws[C_IN][H];
    int tid = threadIdx.x;
    const float* xb = x + (size_t)b * C_IN * NN + (size_t)r * GRID_D;
    for (int idx = tid; idx < C_IN * GRID_D; idx += 256) {
        int c = idx >> 6, n = idx & 63;
        xs[c][n] = xb[(size_t)c * NN + n];
        ws[c][n] = w_in[idx];
    }
    __syncthreads();
    int n = tid >> 2;                // node 0..63
    int j0 = (tid & 3) * 16;         // 16-feat group
    float acc[16];
    #pragma unroll
    for (int t = 0; t < 16; ++t) acc[t] = b_in[j0 + t];
    #pragma unroll
    for (int c = 0; c < C_IN; ++c) {
        float xv = xs[c][n];
        #pragma unroll
        for (int t = 0; t < 16; ++t) acc[t] += xv * ws[c][j0 + t];
    }
    _Float16* hp = h + (size_t)(b * NN + r * GRID_D + n) * H + j0;
    f16x8 o0, o1;
    #pragma unroll
    for (int t = 0; t < 8; ++t) { o0[t] = (_Float16)acc[t]; o1[t] = (_Float16)acc[8 + t]; }
    *(f16x8*)hp = o0;
    *(f16x8*)(hp + 8) = o1;
}

// ---------------------------------------------------------------------------
// Kernel 2: FUSED 3 layers + head, wavefront pipeline, no ring0.
// Block = 768 thr (12 waves) owns 32 output rows of one image (grid 256).
// grp0: h1 from GLOBAL h0 (rows L1/L2-hot, read 3 consecutive steps) -> ringA.
// grp1: h1->h2 (ringA->ringB). grp2: h2->h3+head -> logits.
// Step s: grp g computes row r0-2-2g+s; one barrier/step; ring reads are
// >=1 step older than writes (mod-4 slots, collision-free). Weights: 16
// f16x8/lane in VGPRs, pinned; launch_bounds(768,4) leaves VGPR headroom —
// compiler landed at 80 in R10; <=85 gives 2 blocks/CU (24 waves).
// ---------------------------------------------------------------------------
__global__ __launch_bounds__(768, 4) void k_fused(
    const _Float16* __restrict__ h0, float* __restrict__ logits,
    const _Float16* __restrict__ wtb,      // [3][2][64][64] transposed f16
    const float* __restrict__ cb, const float* __restrict__ lg,
    const float* __restrict__ lb,
    const float* __restrict__ w_head, const float* __restrict__ b_head)
{
    extern __shared__ _Float16 smem[];
    _Float16* ringA = smem;                     // h1 ring [4][4096]
    _Float16* ringB = smem + 16384;             // h2 ring [4][4096]
    float*    pl    = (float*)(smem + 32768);   // 640 f32

    int tid = threadIdx.x, ln = tid & 63, wv = tid >> 6;
    int bid = blockIdx.x;
    int img = bid >> 1, chunk = bid & 1;
    int r0 = chunk << 5;                   // 32 output rows
    const _Float16* hg = h0 + ((size_t)img << 18);

    int grp = wv >> 2;                     // 0,1,2 = layer-1,2,3
    int ct  = wv & 3;                      // col tile
    int lrow = ln & 15, kgrp = ln >> 4;
    int col = ct * 16 + lrow;
    int cs = col & 7;                      // == lrow & 7
    int kq = kgrp * 4;
    bool cl = (col > 0), cr = (col < 63);

    // ---- weights for my group's layer: 16 frags = 64 VGPR, pinned ----
    const _Float16* wg = wtb + grp * 8192;
    f16x8 wsf[2][4], wnf[2][4];
    #pragma unroll
    for (int ks = 0; ks < 2; ++ks) {
        int k0 = ks * 32 + kq * 2;         // ks*32 + kgrp*8
        #pragma unroll
        for (int ft = 0; ft < 4; ++ft) {
            int j = ft * 16 + lrow;
            wsf[ks][ft] = *(const f16x8*)(wg + (j << 6) + k0);
            wnf[ks][ft] = *(const f16x8*)(wg + ((64 + j) << 6) + k0);
        }
    }
    #pragma unroll
    for (int ks = 0; ks < 2; ++ks)
        #pragma unroll
        for (int ft = 0; ft < 4; ++ft)
            asm volatile("" : "+v"(wsf[ks][ft]), "+v"(wnf[ks][ft]));

    // ---- params to LDS ----
    if (tid < 576) {
        int l = tid / 192, r = tid % 192;
        pl[tid] = (r < 64) ? cb[l * 64 + r]
                : (r < 128) ? lg[l * 64 + r - 64] : lb[l * 64 + r - 128];
    } else if (tid < 640) {
        pl[tid] = w_head[tid - 576];
    }
    __syncthreads();

    const float* myp = pl + grp * 192;
    float bh = b_head[0];

    int qoff = -2 - 2 * grp;
    int loC, hiC;
    if (grp == 0)      { loC = (r0 - 2 < 0) ? 0 : r0 - 2; hiC = (r0 + 33 > 63) ? 63 : r0 + 33; }
    else if (grp == 1) { loC = (r0 - 1 < 0) ? 0 : r0 - 1; hiC = (r0 + 32 > 63) ? 63 : r0 + 32; }
    else               { loC = r0;                         hiC = r0 + 31; }

    const _Float16* rin = (grp == 1) ? ringA : ringB;   // grp2 reads ringB
    _Float16* rout      = (grp == 0) ? ringA : ringB;   // grp1 writes ringB

    #pragma unroll 1
    for (int s = 0; s <= 37; ++s) {
        int q = r0 + qoff + s;                 // my group's row this step
        if (q >= loC && q <= hiC) {
            _Float16 hinv = (_Float16)(1.0f / (float)((q > 0) + (q < 63) + cl + cr));
            f16x8 z = {};
            const _Float16* rp = hg + ((size_t)q << 12);    // global row (grp0)
            const _Float16* rc = rin + ((q & 3) << 12);     // ring row (grp1/2)
            const _Float16* ru = rin + (((q - 1) & 3) << 12);
            const _Float16* rd = rin + (((q + 1) & 3) << 12);

            f32x4 acc[4];
            #pragma unroll
            for (int ft = 0; ft < 4; ++ft) acc[ft] = (f32x4){0.f, 0.f, 0.f, 0.f};

            // ---- phase 1: Ws^T @ self^T ----
            #pragma unroll
            for (int ks = 0; ks < 2; ++ks) {
                f16x8 a;
                if (grp == 0) {
                    a = *(const f16x8*)(rp + (col << 6) + ks * 32 + kq * 2);
                } else {
                    int sl = ((ks * 4 + kgrp) ^ cs) << 3;
                    a = *(const f16x8*)(rc + (col << 6) + sl);
                }
                #pragma unroll
                for (int ft = 0; ft < 4; ++ft)
                    acc[ft] = __builtin_amdgcn_mfma_f32_16x16x32_f16(wsf[ks][ft], a, acc[ft], 0, 0, 0);
            }

            // ---- phase 2: Wn^T @ agg^T ----
            #pragma unroll
            for (int ks = 0; ks < 2; ++ks) {
                f16x8 u, d, l, r;
                if (grp == 0) {
                    int k0 = ks * 32 + kq * 2;
                    const _Float16* pc = rp + (col << 6) + k0;
                    u = (q > 0)  ? *(const f16x8*)(pc - 4096) : z;
                    d = (q < 63) ? *(const f16x8*)(pc + 4096) : z;
                    l = cl ? *(const f16x8*)(pc - 64) : z;
                    r = cr ? *(const f16x8*)(pc + 64) : z;
                } else {
                    int c8 = ks * 4 + kgrp;
                    int sl = (c8 ^ cs) << 3;
                    u = (q > 0)  ? *(const f16x8*)(ru + (col << 6) + sl) : z;
                    d = (q < 63) ? *(const f16x8*)(rd + (col << 6) + sl) : z;
                    int cm = col - cl;
                    l = *(const f16x8*)(rc + (cm << 6) + ((c8 ^ (cm & 7)) << 3));
                    if (!cl) l = z;
                    int cp = col + cr;
                    r = *(const f16x8*)(rc + (cp << 6) + ((c8 ^ (cp & 7)) << 3));
                    if (!cr) r = z;
                }
                f16x8 sm = (l + r) + (u + d);
                f16x8 g;
                #pragma unroll
                for (int e = 0; e < 8; ++e) g[e] = sm[e] * hinv;
                #pragma unroll
                for (int ft = 0; ft < 4; ++ft)
                    acc[ft] = __builtin_amdgcn_mfma_f32_16x16x32_f16(wnf[ks][ft], g, acc[ft], 0, 0, 0);
            }

            // ---- epilogue: +bias, LN, residual+ReLU -> ring or logits ----
            float s1 = 0.f, s2 = 0.f;
            #pragma unroll
            for (int ft = 0; ft < 4; ++ft) {
                f32x4 qv = *(const f32x4*)&myp[ft * 16 + kq];
                acc[ft] += qv;
                #pragma unroll
                for (int t = 0; t < 4; ++t) { float xv = acc[ft][t]; s1 += xv; s2 += xv * xv; }
            }
            s1 += __shfl_xor(s1, 16); s1 += __shfl_xor(s1, 32);
            s2 += __shfl_xor(s2, 16); s2 += __shfl_xor(s2, 32);
            float mu   = s1 * (1.0f / H);
            float var  = s2 * (1.0f / H) - mu * mu;
            float rstd = rsqrtf(var + LN_EPS);

            if (grp < 2) {
                _Float16* outp = rout + ((q & 3) << 12) + (col << 6);
                #pragma unroll
                for (int ft = 0; ft < 4; ++ft) {
                    f32x4 lgq = *(const f32x4*)&myp[64 + ft * 16 + kq];
                    f32x4 lbq = *(const f32x4*)&myp[128 + ft * 16 + kq];
                    int slot = (ft * 2 + (kgrp >> 1)) ^ cs;
                    f16x4 rq;
                    if (grp == 0)
                        rq = *(const f16x4*)(rp + (col << 6) + ft * 16 + kq);
                    else
                        rq = *(const f16x4*)(rc + (col << 6) + (slot << 3) + (kgrp & 1) * 4);
                    f16x4 oq;
                    #pragma unroll
                    for (int t = 0; t < 4; ++t) {
                        float o = (float)rq[t]
                                + fmaxf((acc[ft][t] - mu) * rstd * lgq[t] + lbq[t], 0.f);
                        oq[t] = (_Float16)o;
                    }
                    *(f16x4*)(outp + (slot << 3) + (kgrp & 1) * 4) = oq;
                }
            } else {
                float part = 0.f;
                #pragma unroll
                for (int ft = 0; ft < 4; ++ft) {
                    f32x4 lgq = *(const f32x4*)&myp[64 + ft * 16 + kq];
                    f32x4 lbq = *(const f32x4*)&myp[128 + ft * 16 + kq];
                    f32x4 whq = *(const f32x4*)&pl[576 + ft * 16 + kq];
                    int slot = (ft * 2 + (kgrp >> 1)) ^ cs;
                    f16x4 rq = *(const f16x4*)(rc + (col << 6) + (slot << 3) + (kgrp & 1) * 4);
                    #pragma unroll
                    for (int t = 0; t < 4; ++t) {
                        float o = (float)rq[t]
                                + fmaxf((acc[ft][t] - mu) * rstd * lgq[t] + lbq[t], 0.f);
                        part += o * whq[t];
                    }
                }
                part += __shfl_xor(part, 16);
                part += __shfl_xor(part, 32);
                if (kgrp == 0)
                    logits[(size_t)img * NN + q * GRID_D + col] = part + bh;
            }
        }
        __syncthreads();   // publishes ring writes for next step's readers
    }
}

// ---------------------------------------------------------------------------
extern "C" void kernel_launch(void* const* d_in, const int* in_sizes, int n_in,
                              void* d_out, int out_size, void* d_ws, size_t ws_size,
                              hipStream_t stream) {
    const float* x      = (const float*)d_in[0];
    // d_in[1] edge_index: fixed grid 4-neighborhood -> computed as stencil, unused
    const float* w_in   = (const float*)d_in[2];
    const float* b_in   = (const float*)d_in[3];
    const float* w_self = (const float*)d_in[4];
    const float* w_neigh= (const float*)d_in[5];
    const float* conv_b = (const float*)d_in[6];
    const float* ln_g   = (const float*)d_in[7];
    const float* ln_b   = (const float*)d_in[8];
    const float* w_head = (const float*)d_in[9];
    const float* b_head = (const float*)d_in[10];
    float* out = (float*)d_out;

    char* base = (char*)d_ws;
    const size_t HBYTES = (size_t)B_SZ * NN * H * sizeof(_Float16);   // 64 MiB
    _Float16* h_a = (_Float16*)base;
    _Float16* wtb = (_Float16*)(base + HBYTES);                       // 48 KiB

    (void)hipFuncSetAttribute(reinterpret_cast<const void*>(&k_fused),
                              hipFuncAttributeMaxDynamicSharedMemorySize, SMEM_BYTES);

    k_prep<<<96, 256, 0, stream>>>(w_self, w_neigh, wtb);
    k_inproj<<<B_SZ * GRID_D, 256, 0, stream>>>(x, w_in, b_in, h_a);
    k_fused<<<B_SZ * 2, 768, SMEM_BYTES, stream>>>(
        h_a, out, wtb, conv_b, ln_g, ln_b, w_head, b_head);
}